// Round 1
// baseline (10086.961 us; speedup 1.0000x reference)
//
#include <hip/hip_runtime.h>
#include <math.h>

// Problem constants: T=512, B=64, I=256, H=1024, O=256
// d_out layout: outputs [512*64][256] fp32, then hidden_states [512*64][1024] fp32.

typedef __attribute__((ext_vector_type(8))) short s16x8;
typedef __attribute__((ext_vector_type(4))) short s16x4;
typedef __attribute__((ext_vector_type(4))) float f32x4;

__device__ __forceinline__ short f2bf(float f) {
  union { float f; unsigned u; } v; v.f = f;
  unsigned r = v.u + 0x7FFFu + ((v.u >> 16) & 1u);  // RNE
  return (short)(r >> 16);
}

__device__ __forceinline__ f32x4 mfma16(s16x8 a, s16x8 b, f32x4 c) {
  return __builtin_amdgcn_mfma_f32_16x16x32_bf16(a, b, c, 0, 0, 0);
}

// ---------------- converters / init ----------------

__global__ void cvt_bf16x4(const float* __restrict__ in, short* __restrict__ out, int n4) {
  int i = blockIdx.x * 256 + threadIdx.x;
  if (i < n4) {
    const float4 v = ((const float4*)in)[i];
    s16x4 o = { f2bf(v.x), f2bf(v.y), f2bf(v.z), f2bf(v.w) };
    ((s16x4*)out)[i] = o;
  }
}

// staging: [2 slots][64 rows][1024] bf16. Slot 1 = h_{-1} = broadcast h0.
__global__ void init_staging(const float* __restrict__ h0, short* __restrict__ staging) {
  int i = blockIdx.x * 256 + threadIdx.x;  // 2*64*1024 = 131072
  if (i < 131072) {
    int slot = i >> 16;
    int k = i & 1023;
    staging[i] = (slot == 1) ? f2bf(h0[k]) : (short)0;
  }
}

// ---------------- generic NT GEMM: out[M][N] = A[M][K](bf16) * B[N][K](bf16)^T + bias ----------------
// grid (M/64, N/64), block 256 (4 waves, each a 32x32 tile as 2x2 of 16x16 MFMA tiles).

template <int K>
__global__ __launch_bounds__(256) void gemm_nt_bias(
    const short* __restrict__ A, const short* __restrict__ B,
    const float* __restrict__ bias, float* __restrict__ out, int N) {
  const int tid = threadIdx.x;
  const int lane = tid & 63, wv = tid >> 6;
  const int m0 = blockIdx.x * 64 + (wv & 1) * 32;
  const int n0 = blockIdx.y * 64 + (wv >> 1) * 32;
  const int lm = lane & 15, q = lane >> 4;

  const short* a0p = A + (m0 + lm) * K + q * 8;
  const short* a1p = a0p + 16 * K;
  const short* b0p = B + (n0 + lm) * K + q * 8;
  const short* b1p = b0p + 16 * K;

  f32x4 c00 = {0.f,0.f,0.f,0.f}, c01 = {0.f,0.f,0.f,0.f};
  f32x4 c10 = {0.f,0.f,0.f,0.f}, c11 = {0.f,0.f,0.f,0.f};

#pragma unroll
  for (int kk = 0; kk < K; kk += 32) {
    s16x8 a0 = *(const s16x8*)(a0p + kk);
    s16x8 a1 = *(const s16x8*)(a1p + kk);
    s16x8 b0 = *(const s16x8*)(b0p + kk);
    s16x8 b1 = *(const s16x8*)(b1p + kk);
    c00 = mfma16(a0, b0, c00);
    c01 = mfma16(a0, b1, c01);
    c10 = mfma16(a1, b0, c10);
    c11 = mfma16(a1, b1, c11);
  }

  const int col0 = n0 + lm;
  const float bi0 = bias[col0], bi1 = bias[col0 + 16];
#pragma unroll
  for (int r = 0; r < 4; ++r) {
    int row = m0 + q * 4 + r;
    out[row * N + col0]        = c00[r] + bi0;
    out[row * N + col0 + 16]   = c01[r] + bi1;
    out[(row + 16) * N + col0]      = c10[r] + bi0;
    out[(row + 16) * N + col0 + 16] = c11[r] + bi1;
  }
}

// ---------------- recurrent kernel ----------------
// 256 WGs of 64 threads (1 wave). group g = bid&7 owns batch rows [8g,8g+8);
// col-wg c = bid>>3 owns hidden cols [32c,32c+32). wR slice lives in 256 VGPRs
// as pre-packed MFMA B-fragments. Data-flow sync via per-(t,g,wg) flags.

__global__ __launch_bounds__(64, 1) void rnn_recur(
    const float* __restrict__ wR,     // [1024][1024] fp32, k-major
    float* __restrict__ hid,          // [512*64][1024] fp32: xp on entry, h on exit
    short* __restrict__ hs_bf,        // [512*64][1024] bf16 copy of h (for phase C)
    short* __restrict__ staging,      // [2][64][1024] bf16 ring of h
    int* __restrict__ flags)          // [512][8][32]
{
  const int lane = threadIdx.x;
  const int g = blockIdx.x & 7;
  const int c = blockIdx.x >> 3;
  const int m = lane & 15, q = lane >> 4;
  const int rowbase = g * 8;
  const int colbase = c * 32;

  // --- one-time: pack wR[:, colbase..colbase+32) into B-fragments in registers ---
  // B-frag for 16x16x32: lane holds B[k = q*8 + j][n = lm] of each 32-k chunk.
  s16x8 bf[32][2];
#pragma unroll
  for (int cc = 0; cc < 32; ++cc) {
#pragma unroll
    for (int tn = 0; tn < 2; ++tn) {
      const int kb = cc * 32 + q * 8;
      const int n = colbase + tn * 16 + m;
      s16x8 v;
#pragma unroll
      for (int j = 0; j < 8; ++j) v[j] = f2bf(wR[(kb + j) * 1024 + n]);
      bf[cc][tn] = v;
    }
  }

  const int arow = rowbase + (m & 7);  // lanes m>=8 duplicate rows 0..7; D rows 8..15 discarded
  const int gr = rowbase + q * 4;      // epilogue rows (valid when q<2)

#pragma unroll 1
  for (int t = 0; t < 512; ++t) {
    const int tb = t * 64;

    // prefetch xp (independent of flags) to hide LLC latency behind the poll
    float xp0[4] = {0.f,0.f,0.f,0.f}, xp1[4] = {0.f,0.f,0.f,0.f};
    if (q < 2) {
#pragma unroll
      for (int r = 0; r < 4; ++r) {
        int ro = (tb + gr + r) * 1024;
        xp0[r] = hid[ro + colbase + m];
        xp1[r] = hid[ro + colbase + 16 + m];
      }
    }

    if (t > 0) {
      const int* fl = flags + (t - 1) * 256 + g * 32;
      for (;;) {
        int v = 1;
        if (lane < 32) v = __hip_atomic_load(fl + lane, __ATOMIC_RELAXED, __HIP_MEMORY_SCOPE_AGENT);
        if (__all(v != 0)) break;
      }
      __threadfence();  // acquire: make producers' staging writes visible
    }

    const short* st = staging + (((t + 1) & 1) << 16) + arow * 1024 + q * 8;

    f32x4 cA0 = {0.f,0.f,0.f,0.f}, cA1 = {0.f,0.f,0.f,0.f};
    f32x4 cB0 = {0.f,0.f,0.f,0.f}, cB1 = {0.f,0.f,0.f,0.f};
#pragma unroll
    for (int cc = 0; cc < 32; ++cc) {
      s16x8 a = *(const s16x8*)(st + cc * 32);
      if (cc & 1) {
        cB0 = mfma16(a, bf[cc][0], cB0);
        cB1 = mfma16(a, bf[cc][1], cB1);
      } else {
        cA0 = mfma16(a, bf[cc][0], cA0);
        cA1 = mfma16(a, bf[cc][1], cA1);
      }
    }
    f32x4 s0 = cA0 + cB0;
    f32x4 s1 = cA1 + cB1;

    if (q < 2) {
#pragma unroll
      for (int r = 0; r < 4; ++r) {
        int ro = (tb + gr + r) * 1024;
        float h0v = tanhf(s0[r] + xp0[r]);
        float h1v = tanhf(s1[r] + xp1[r]);
        hid[ro + colbase + m] = h0v;
        hid[ro + colbase + 16 + m] = h1v;
        short hb0 = f2bf(h0v), hb1 = f2bf(h1v);
        hs_bf[ro + colbase + m] = hb0;
        hs_bf[ro + colbase + 16 + m] = hb1;
        int so = ((t & 1) << 16) + (gr + r) * 1024;
        staging[so + colbase + m] = hb0;
        staging[so + colbase + 16 + m] = hb1;
      }
    }

    __threadfence();  // release: drain + write back before flagging
    if (lane == 0)
      __hip_atomic_store(flags + t * 256 + g * 32 + c, 1,
                         __ATOMIC_RELEASE, __HIP_MEMORY_SCOPE_AGENT);
  }
}

// ---------------- host ----------------

extern "C" void kernel_launch(void* const* d_in, const int* in_sizes, int n_in,
                              void* d_out, int out_size, void* d_ws, size_t ws_size,
                              hipStream_t stream) {
  const float* x  = (const float*)d_in[0];
  const float* h0 = (const float*)d_in[1];
  const float* wI = (const float*)d_in[2];
  const float* wR = (const float*)d_in[3];
  const float* wO = (const float*)d_in[4];
  const float* bR = (const float*)d_in[5];
  const float* bO = (const float*)d_in[6];

  float* outputs = (float*)d_out;                    // [512*64][256]
  float* hid = outputs + 512 * 64 * 256;             // [512*64][1024]

  // workspace layout (bytes): ~85.7 MB total
  short* x_bf    = (short*)d_ws;                     // 8,388,608 bf16
  short* wI_bf   = x_bf + 8388608;                   // 262,144
  short* wO_bf   = wI_bf + 262144;                   // 262,144
  short* hs_bf   = wO_bf + 262144;                   // 33,554,432
  short* staging = hs_bf + 33554432;                 // 131,072
  int*   flags   = (int*)(staging + 131072);         // 131,072 ints

  hipMemsetAsync(flags, 0, 512 * 256 * sizeof(int), stream);
  cvt_bf16x4<<<8192, 256, 0, stream>>>(x, x_bf, 2097152);
  cvt_bf16x4<<<256, 256, 0, stream>>>(wI, wI_bf, 65536);
  cvt_bf16x4<<<256, 256, 0, stream>>>(wO, wO_bf, 65536);
  init_staging<<<512, 256, 0, stream>>>(h0, staging);

  // Phase A: xp = x*wI^T + bR  -> hidden region (in-place seed for recurrence)
  gemm_nt_bias<256><<<dim3(512, 16), 256, 0, stream>>>(x_bf, wI_bf, bR, hid, 1024);
  // Phase B: sequential recurrence
  rnn_recur<<<256, 64, 0, stream>>>(wR, hid, hs_bf, staging, flags);
  // Phase C: outputs = h*wO^T + bO
  gemm_nt_bias<1024><<<dim3(512, 4), 256, 0, stream>>>(hs_bf, wO_bf, bO, outputs, 256);
}

// Round 4
// 4267.611 us; speedup vs baseline: 2.3636x; 2.3636x over previous
//
#include <hip/hip_runtime.h>
#include <math.h>

// Problem constants: T=512, B=64, I=256, H=1024, O=256
// d_out layout: outputs [512*64][256] fp32, then hidden_states [512*64][1024] fp32.

typedef __attribute__((ext_vector_type(8))) short s16x8;
typedef __attribute__((ext_vector_type(4))) short s16x4;
typedef __attribute__((ext_vector_type(4))) float f32x4;

__device__ __forceinline__ short f2bf(float f) {
  union { float f; unsigned u; } v; v.f = f;
  unsigned r = v.u + 0x7FFFu + ((v.u >> 16) & 1u);  // RNE
  return (short)(r >> 16);
}

__device__ __forceinline__ f32x4 mfma16(s16x8 a, s16x8 b, f32x4 c) {
  return __builtin_amdgcn_mfma_f32_16x16x32_bf16(a, b, c, 0, 0, 0);
}

// tanh via v_exp_f32: t = 1 - 2/(e^{2x}+1). Monotone-safe at +-inf, no NaN.
__device__ __forceinline__ float fast_tanh(float x) {
  float e = __expf(2.0f * x);
  return 1.0f - 2.0f * __builtin_amdgcn_rcpf(e + 1.0f);
}

// ---------------- converters / init ----------------

__global__ void cvt_bf16x4(const float* __restrict__ in, short* __restrict__ out, int n4) {
  int i = blockIdx.x * 256 + threadIdx.x;
  if (i < n4) {
    const float4 v = ((const float4*)in)[i];
    s16x4 o = { f2bf(v.x), f2bf(v.y), f2bf(v.z), f2bf(v.w) };
    ((s16x4*)out)[i] = o;
  }
}

// staging: [2 slots][64 rows][1024] bf16. Slot 1 = h_{-1} = broadcast h0.
__global__ void init_staging(const float* __restrict__ h0, short* __restrict__ staging) {
  int i = blockIdx.x * 256 + threadIdx.x;  // 2*64*1024 = 131072
  if (i < 131072) {
    int slot = i >> 16;
    int k = i & 1023;
    staging[i] = (slot == 1) ? f2bf(h0[k]) : (short)0;
  }
}

// ---------------- generic NT GEMM: out[M][N] = A[M][K](bf16) * B[N][K](bf16)^T + bias ----------------

template <int K>
__global__ __launch_bounds__(256) void gemm_nt_bias(
    const short* __restrict__ A, const short* __restrict__ B,
    const float* __restrict__ bias, float* __restrict__ out, int N) {
  const int tid = threadIdx.x;
  const int lane = tid & 63, wv = tid >> 6;
  const int m0 = blockIdx.x * 64 + (wv & 1) * 32;
  const int n0 = blockIdx.y * 64 + (wv >> 1) * 32;
  const int lm = lane & 15, q = lane >> 4;

  const short* a0p = A + (m0 + lm) * K + q * 8;
  const short* a1p = a0p + 16 * K;
  const short* b0p = B + (n0 + lm) * K + q * 8;
  const short* b1p = b0p + 16 * K;

  f32x4 c00 = {0.f,0.f,0.f,0.f}, c01 = {0.f,0.f,0.f,0.f};
  f32x4 c10 = {0.f,0.f,0.f,0.f}, c11 = {0.f,0.f,0.f,0.f};

#pragma unroll
  for (int kk = 0; kk < K; kk += 32) {
    s16x8 a0 = *(const s16x8*)(a0p + kk);
    s16x8 a1 = *(const s16x8*)(a1p + kk);
    s16x8 b0 = *(const s16x8*)(b0p + kk);
    s16x8 b1 = *(const s16x8*)(b1p + kk);
    c00 = mfma16(a0, b0, c00);
    c01 = mfma16(a0, b1, c01);
    c10 = mfma16(a1, b0, c10);
    c11 = mfma16(a1, b1, c11);
  }

  const int col0 = n0 + lm;
  const float bi0 = bias[col0], bi1 = bias[col0 + 16];
#pragma unroll
  for (int r = 0; r < 4; ++r) {
    int row = m0 + q * 4 + r;
    out[row * N + col0]        = c00[r] + bi0;
    out[row * N + col0 + 16]   = c01[r] + bi1;
    out[(row + 16) * N + col0]      = c10[r] + bi0;
    out[(row + 16) * N + col0 + 16] = c11[r] + bi1;
  }
}

// ---------------- recurrent kernel ----------------
// 256 WGs of 64 threads (1 wave). group g = bid&7 owns batch rows [8g,8g+8);
// col-wg c = bid>>3 owns hidden cols [32c,32c+32). wR slice lives in 256 regs.
// Cross-WG h exchange: relaxed SYSTEM-scope atomics (sc0 sc1, bypass L1+L2,
// coherence point = Infinity Cache). NO fences (R1's agent fences caused a
// 266 GB buffer_wbl2/buffer_inv storm). NO inline-asm loads (R2 hazard).
// Per-(t,group) counter: producers fetch_add 1, consumers poll until 32.
// R3 bug fixed here: packed-store col offset is (lane&7)*4, NOT *8 — each
// lane's 8B chunk covers 4 bf16 cols of local row lane>>3.

__global__ __launch_bounds__(64, 1) void rnn_recur(
    const float* __restrict__ wR,     // [1024][1024] fp32, k-major
    float* __restrict__ hid,          // [512*64][1024] fp32: xp on entry, h on exit
    short* __restrict__ hs_bf,        // [512*64][1024] bf16 copy of h (for phase C)
    short* __restrict__ staging,      // [2][64][1024] bf16 ring of h
    int* __restrict__ flags)          // [512][8] counters
{
  __shared__ short lh[256];           // 8 rows x 32 cols bf16 repack buffer

  const int lane = threadIdx.x;
  const int g = blockIdx.x & 7;
  const int c = blockIdx.x >> 3;
  const int m = lane & 15, q = lane >> 4;
  const int rowbase = g * 8;
  const int colbase = c * 32;

  // --- one-time: pack wR[:, colbase..colbase+32) into B-fragments in registers ---
  s16x8 bf[32][2];
#pragma unroll
  for (int cc = 0; cc < 32; ++cc) {
#pragma unroll
    for (int tn = 0; tn < 2; ++tn) {
      const int kb = cc * 32 + q * 8;
      const int n = colbase + tn * 16 + m;
      s16x8 v;
#pragma unroll
      for (int j = 0; j < 8; ++j) v[j] = f2bf(wR[(kb + j) * 1024 + n]);
      bf[cc][tn] = v;
    }
  }

  const int arow = rowbase + (m & 7);  // lanes m>=8 duplicate rows 0..7
  const int gr = rowbase + q * 4;      // epilogue rows (valid when q<2)
  const int lr = q * 4;                // local row base in lh
  // packed-store mapping: lane i handles 8 bytes = 4 cols: row i>>3, col (i&7)*4
  const int prow = lane >> 3, pcol = (lane & 7) * 4;

  union LD { long long l[2]; s16x8 s; };

#pragma unroll 1
  for (int t = 0; t < 512; ++t) {
    const int tb = t * 64;

    // prefetch xp (independent of the flag) to hide latency behind the poll
    float xp0[4] = {0.f,0.f,0.f,0.f}, xp1[4] = {0.f,0.f,0.f,0.f};
    if (q < 2) {
#pragma unroll
      for (int r = 0; r < 4; ++r) {
        int ro = (tb + gr + r) * 1024;
        xp0[r] = hid[ro + colbase + m];
        xp1[r] = hid[ro + colbase + 16 + m];
      }
    }

    if (t > 0) {
      const int* cnt = flags + (t - 1) * 8 + g;
      while (__hip_atomic_load(cnt, __ATOMIC_RELAXED, __HIP_MEMORY_SCOPE_SYSTEM) < 32) { }
      asm volatile("" ::: "memory");  // compiler barrier: no load hoisting above the poll
    }

    const short* st = staging + (((t + 1) & 1) << 16) + arow * 1024 + q * 8;

    f32x4 cA0 = {0.f,0.f,0.f,0.f}, cA1 = {0.f,0.f,0.f,0.f};
    f32x4 cB0 = {0.f,0.f,0.f,0.f}, cB1 = {0.f,0.f,0.f,0.f};

    // 4 batches of 8 chunks; batch b+1 loads issue before batch b MFMAs
    LD buf[2][8];
#pragma unroll
    for (int j = 0; j < 8; ++j) {
      const short* p = st + j * 32;
      buf[0][j].l[0] = __hip_atomic_load((const long long*)p,     __ATOMIC_RELAXED, __HIP_MEMORY_SCOPE_SYSTEM);
      buf[0][j].l[1] = __hip_atomic_load((const long long*)(p+4), __ATOMIC_RELAXED, __HIP_MEMORY_SCOPE_SYSTEM);
    }
#pragma unroll
    for (int b = 0; b < 4; ++b) {
      if (b < 3) {
#pragma unroll
        for (int j = 0; j < 8; ++j) {
          const short* p = st + (b + 1) * 256 + j * 32;
          buf[(b+1)&1][j].l[0] = __hip_atomic_load((const long long*)p,     __ATOMIC_RELAXED, __HIP_MEMORY_SCOPE_SYSTEM);
          buf[(b+1)&1][j].l[1] = __hip_atomic_load((const long long*)(p+4), __ATOMIC_RELAXED, __HIP_MEMORY_SCOPE_SYSTEM);
        }
      }
#pragma unroll
      for (int j = 0; j < 8; ++j) {
        const int cc = b * 8 + j;
        s16x8 a = buf[b&1][j].s;
        if (cc & 1) {
          cB0 = mfma16(a, bf[cc][0], cB0);
          cB1 = mfma16(a, bf[cc][1], cB1);
        } else {
          cA0 = mfma16(a, bf[cc][0], cA0);
          cA1 = mfma16(a, bf[cc][1], cA1);
        }
      }
    }
    f32x4 s0 = cA0 + cB0;
    f32x4 s1 = cA1 + cB1;

    // tanh + repack through LDS (512B, single wave)
    float h0v[4], h1v[4];
    if (q < 2) {
#pragma unroll
      for (int r = 0; r < 4; ++r) {
        h0v[r] = fast_tanh(s0[r] + xp0[r]);
        h1v[r] = fast_tanh(s1[r] + xp1[r]);
        lh[(lr + r) * 32 + m]      = f2bf(h0v[r]);
        lh[(lr + r) * 32 + 16 + m] = f2bf(h1v[r]);
      }
    }
    __syncthreads();

    // one 8B packed value per lane -> staging (protocol) + hs_bf (phase C)
    long long pk = ((const long long*)lh)[lane];
    {
      long long* sp = (long long*)(staging + ((t & 1) << 16)
                                   + (rowbase + prow) * 1024 + colbase + pcol);
      __hip_atomic_store(sp, pk, __ATOMIC_RELAXED, __HIP_MEMORY_SCOPE_SYSTEM);
      *(long long*)(hs_bf + (tb + rowbase + prow) * 1024 + colbase + pcol) = pk;
    }
    __syncthreads();  // lh reads done before next step's writes

    asm volatile("s_waitcnt vmcnt(0)" ::: "memory");  // staging stores acked at L3
    if (lane == 0)
      __hip_atomic_fetch_add(flags + t * 8 + g, 1,
                             __ATOMIC_RELAXED, __HIP_MEMORY_SCOPE_SYSTEM);

    // non-protocol fp32 h stores drain whenever (kernel-end flush covers phase C)
    if (q < 2) {
#pragma unroll
      for (int r = 0; r < 4; ++r) {
        int ro = (tb + gr + r) * 1024;
        hid[ro + colbase + m] = h0v[r];
        hid[ro + colbase + 16 + m] = h1v[r];
      }
    }
  }
}

// ---------------- host ----------------

extern "C" void kernel_launch(void* const* d_in, const int* in_sizes, int n_in,
                              void* d_out, int out_size, void* d_ws, size_t ws_size,
                              hipStream_t stream) {
  const float* x  = (const float*)d_in[0];
  const float* h0 = (const float*)d_in[1];
  const float* wI = (const float*)d_in[2];
  const float* wR = (const float*)d_in[3];
  const float* wO = (const float*)d_in[4];
  const float* bR = (const float*)d_in[5];
  const float* bO = (const float*)d_in[6];

  float* outputs = (float*)d_out;                    // [512*64][256]
  float* hid = outputs + 512 * 64 * 256;             // [512*64][1024]

  // workspace layout: ~85.7 MB total
  short* x_bf    = (short*)d_ws;                     // 8,388,608 bf16
  short* wI_bf   = x_bf + 8388608;                   // 262,144
  short* wO_bf   = wI_bf + 262144;                   // 262,144
  short* hs_bf   = wO_bf + 262144;                   // 33,554,432
  short* staging = hs_bf + 33554432;                 // 131,072
  int*   flags   = (int*)(staging + 131072);         // 512*8 counters

  hipMemsetAsync(flags, 0, 512 * 8 * sizeof(int), stream);
  cvt_bf16x4<<<8192, 256, 0, stream>>>(x, x_bf, 2097152);
  cvt_bf16x4<<<256, 256, 0, stream>>>(wI, wI_bf, 65536);
  cvt_bf16x4<<<256, 256, 0, stream>>>(wO, wO_bf, 65536);
  init_staging<<<512, 256, 0, stream>>>(h0, staging);

  // Phase A: xp = x*wI^T + bR  -> hidden region (in-place seed for recurrence)
  gemm_nt_bias<256><<<dim3(512, 16), 256, 0, stream>>>(x_bf, wI_bf, bR, hid, 1024);
  // Phase B: sequential recurrence
  rnn_recur<<<256, 64, 0, stream>>>(wR, hid, hs_bf, staging, flags);
  // Phase C: outputs = h*wO^T + bO
  gemm_nt_bias<1024><<<dim3(512, 4), 256, 0, stream>>>(hs_bf, wO_bf, bO, outputs, 256);
}